// Round 3
// baseline (261.297 us; speedup 1.0000x reference)
//
#include <hip/hip_runtime.h>

#define G    128
#define G3   (G * G * G)          // 2097152
#define TDIM 32
#define NTOT (TDIM * G3)          // 67108864
#define NBYTES_OUT (NTOT / 8)     // 8388608
#define DECAY 0.95f
#define DTH   0.01f
#define NBLK1 (TDIM * 512)        // 16384 blocks, each = one (t, 16^3 cube)

typedef float f32x4 __attribute__((ext_vector_type(4)));
typedef float f32x2 __attribute__((ext_vector_type(2)));

// instant-ngp style bit expansion (<=10-bit inputs)
__device__ __forceinline__ unsigned expand3(unsigned v) {
    v = (v * 0x00010001u) & 0xFF0000FFu;
    v = (v * 0x00000101u) & 0x0F00F00Fu;
    v = (v * 0x00000011u) & 0xC30C30C3u;
    v = (v * 0x00000005u) & 0x49249249u;
    return v;
}
// extract every 3rd bit starting at bit 0
__device__ __forceinline__ unsigned compact3(unsigned v) {
    v &= 0x49249249u;
    v = (v | (v >> 2))  & 0xC30C30C3u;
    v = (v | (v >> 4))  & 0x0F00F00Fu;
    v = (v | (v >> 8))  & 0xFF0000FFu;
    v = (v | (v >> 16)) & 0x000003FFu;
    return v;
}
// LDS swizzle: inject morton bits 7,8,10 into bank bits 2,3,4 (bits 0,1 preserved -> b128 ok)
__device__ __forceinline__ int swz(int m) {
    return (((m >> 7) & 1) << 2) ^ (((m >> 8) & 1) << 3) ^ (((m >> 10) & 1) << 4);
}

__device__ __forceinline__ f32x4 merge4(f32x4 v, f32x4 s) {
    f32x4 r;
    r.x = (v.x >= 0.f && s.x >= 0.f) ? fmaxf(v.x * DECAY, s.x) : v.x;
    r.y = (v.y >= 0.f && s.y >= 0.f) ? fmaxf(v.y * DECAY, s.y) : v.y;
    r.z = (v.z >= 0.f && s.z >= 0.f) ? fmaxf(v.z * DECAY, s.z) : v.z;
    r.w = (v.w >= 0.f && s.w >= 0.f) ? fmaxf(v.w * DECAY, s.w) : v.w;
    return r;
}

// One block = one (t, 16^3 cube). Phase A: coalesced sigma -> LDS morton transpose.
// Phase B: each thread owns 16 consecutive morton elems (2 bitfield bytes).
__global__ __launch_bounds__(256, 6) void
pass1(const float* __restrict__ dg, const float* __restrict__ sg,
      float* __restrict__ out_grid, float* __restrict__ out_bits,
      float* __restrict__ partials)
{
    __shared__ float smem[4096];          // 16 KB
    __shared__ float wsum[4];
    const int blk  = blockIdx.x;          // t*512 + cube_morton
    const int t    = blk >> 9;
    const int cube = blk & 511;
    const int base = t * G3;
    const int tid  = threadIdx.x;
    const int jg0  = base + (cube << 12) + (tid << 4);   // first of 16 morton elems

    // ---- issue density loads EARLY (independent of LDS phase) ----
    const f32x4* dgp = reinterpret_cast<const f32x4*>(dg + jg0);
    const f32x4 v0 = __builtin_nontemporal_load(dgp + 0);
    const f32x4 v1 = __builtin_nontemporal_load(dgp + 1);
    const f32x4 v2 = __builtin_nontemporal_load(dgp + 2);
    const f32x4 v3 = __builtin_nontemporal_load(dgp + 3);

    // ---- Phase A: linear sigma -> LDS (local morton, swizzled) ----
    const unsigned Xc = compact3((unsigned)cube);
    const unsigned Yc = compact3((unsigned)cube >> 1);
    const unsigned Zc = compact3((unsigned)cube >> 2);
    const float* __restrict__ sgt = sg + base + (int)((Xc << 18) | (Yc << 11) | (Zc << 4));
    #pragma unroll
    for (int k = 0; k < 4; ++k) {
        const int c  = tid + (k << 8);              // 0..1023
        const int lx = c >> 6;
        const int ly = (c >> 2) & 15;
        const int lz = (c & 3) << 2;
        const f32x4 s = *reinterpret_cast<const f32x4*>(sgt + (lx << 14) + (ly << 7) + lz);
        const int m  = (int)(expand3((unsigned)lx) | (expand3((unsigned)ly) << 1)
                           | (expand3((unsigned)lz) << 2));   // bits 2,5 clear
        const int mb = m ^ swz(m);
        smem[mb]      = s.x;   // z+0
        smem[mb ^ 4]  = s.y;   // z+1 (morton +4)
        smem[mb ^ 32] = s.z;   // z+2 (morton +32)
        smem[mb ^ 36] = s.w;   // z+3
    }
    __syncthreads();

    // ---- Phase B: 16 consecutive morton elems, batched LDS reads ----
    const int j = tid << 4;
    const int b = j ^ swz(j);                       // 16B-aligned (swz touches bits 2..4)
    const f32x4 s0 = *reinterpret_cast<const f32x4*>(&smem[b]);
    const f32x4 s1 = *reinterpret_cast<const f32x4*>(&smem[b ^ 4]);
    const f32x4 s2 = *reinterpret_cast<const f32x4*>(&smem[b ^ 8]);
    const f32x4 s3 = *reinterpret_cast<const f32x4*>(&smem[b ^ 12]);

    const f32x4 r0 = merge4(v0, s0);
    const f32x4 r1 = merge4(v1, s1);
    const f32x4 r2 = merge4(v2, s2);
    const f32x4 r3 = merge4(v3, s3);

    f32x4* ogp = reinterpret_cast<f32x4*>(out_grid + jg0);
    __builtin_nontemporal_store(r0, ogp + 0);
    __builtin_nontemporal_store(r1, ogp + 1);
    __builtin_nontemporal_store(r2, ogp + 2);
    __builtin_nontemporal_store(r3, ogp + 3);

    float lsum = fmaxf(r0.x, 0.f) + fmaxf(r0.y, 0.f) + fmaxf(r0.z, 0.f) + fmaxf(r0.w, 0.f)
               + fmaxf(r1.x, 0.f) + fmaxf(r1.y, 0.f) + fmaxf(r1.z, 0.f) + fmaxf(r1.w, 0.f)
               + fmaxf(r2.x, 0.f) + fmaxf(r2.y, 0.f) + fmaxf(r2.z, 0.f) + fmaxf(r2.w, 0.f)
               + fmaxf(r3.x, 0.f) + fmaxf(r3.y, 0.f) + fmaxf(r3.z, 0.f) + fmaxf(r3.w, 0.f);

    // two full bitfield bytes per thread (assuming thresh == DTH; fixed up iff mean < DTH)
    const int byte0 = (r0.x > DTH ? 1 : 0)  | (r0.y > DTH ? 2 : 0)  |
                      (r0.z > DTH ? 4 : 0)  | (r0.w > DTH ? 8 : 0)  |
                      (r1.x > DTH ? 16 : 0) | (r1.y > DTH ? 32 : 0) |
                      (r1.z > DTH ? 64 : 0) | (r1.w > DTH ? 128 : 0);
    const int byte1 = (r2.x > DTH ? 1 : 0)  | (r2.y > DTH ? 2 : 0)  |
                      (r2.z > DTH ? 4 : 0)  | (r2.w > DTH ? 8 : 0)  |
                      (r3.x > DTH ? 16 : 0) | (r3.y > DTH ? 32 : 0) |
                      (r3.z > DTH ? 64 : 0) | (r3.w > DTH ? 128 : 0);
    f32x2 bb; bb.x = (float)byte0; bb.y = (float)byte1;
    __builtin_nontemporal_store(bb, reinterpret_cast<f32x2*>(out_bits + (jg0 >> 3)));

    // block reduction of clip-sum (4 waves)
    #pragma unroll
    for (int off = 32; off; off >>= 1) lsum += __shfl_down(lsum, off, 64);
    if ((tid & 63) == 0) wsum[tid >> 6] = lsum;
    __syncthreads();
    if (tid == 0)
        partials[blk] = wsum[0] + wsum[1] + wsum[2] + wsum[3];
}

__global__ __launch_bounds__(1024) void
reduce_thresh(const float* __restrict__ partials, float* __restrict__ thresh)
{
    float s = 0.f;
    for (int i = threadIdx.x; i < NBLK1; i += 1024) s += partials[i];
    #pragma unroll
    for (int off = 32; off; off >>= 1) s += __shfl_down(s, off, 64);
    __shared__ float wsum[16];
    if ((threadIdx.x & 63) == 0) wsum[threadIdx.x >> 6] = s;
    __syncthreads();
    if (threadIdx.x == 0) {
        float tot = 0.f;
        #pragma unroll
        for (int i = 0; i < 16; ++i) tot += wsum[i];
        thresh[0] = fminf(tot / (float)NTOT, DTH);
    }
}

// Fallback: only does work if mean < DTH (thresh != DTH). Early-exits otherwise.
__global__ __launch_bounds__(256) void
fix_bits(const float* __restrict__ grid, const float* __restrict__ thresh,
         float* __restrict__ out_bits)
{
    const float th = thresh[0];
    if (th == DTH) return;                        // common case: nothing to do
    const int n = blockIdx.x * 256 + threadIdx.x; // byte index < NBYTES_OUT
    const float4* g = reinterpret_cast<const float4*>(grid) + (n << 1);
    const float4 a = g[0], b = g[1];
    int byte = (a.x > th ? 1 : 0)   | (a.y > th ? 2 : 0)   |
               (a.z > th ? 4 : 0)   | (a.w > th ? 8 : 0)   |
               (b.x > th ? 16 : 0)  | (b.y > th ? 32 : 0)  |
               (b.z > th ? 64 : 0)  | (b.w > th ? 128 : 0);
    out_bits[n] = (float)byte;
}

extern "C" void kernel_launch(void* const* d_in, const int* in_sizes, int n_in,
                              void* d_out, int out_size, void* d_ws, size_t ws_size,
                              hipStream_t stream)
{
    const float* dg = (const float*)d_in[0];   // density_grid [T,1,G^3]
    const float* sg = (const float*)d_in[1];   // sigmas       [T,1,G^3]
    float* out_grid = (float*)d_out;           // [T,1,G^3]
    float* out_bits = out_grid + NTOT;         // [T, G^3/8] as float values
    float* partials = (float*)d_ws;            // NBLK1 floats
    float* thresh   = partials + NBLK1;        // 1 float

    pass1<<<NBLK1, 256, 0, stream>>>(dg, sg, out_grid, out_bits, partials);
    reduce_thresh<<<1, 1024, 0, stream>>>(partials, thresh);
    fix_bits<<<NBYTES_OUT / 256, 256, 0, stream>>>(out_grid, thresh, out_bits);
}

// Round 4
// 180.500 us; speedup vs baseline: 1.4476x; 1.4476x over previous
//
#include <hip/hip_runtime.h>

#define G    128
#define G3   (G * G * G)          // 2097152
#define TDIM 32
#define NTOT (TDIM * G3)          // 67108864
#define NBYTES_OUT (NTOT / 8)     // 8388608
#define DECAY 0.95f
#define DTH   0.01f
#define NBLK1 (TDIM * 512)        // 16384 blocks, each = one (t, 16^3 cube)

typedef float f32x4 __attribute__((ext_vector_type(4)));
typedef float f32x2 __attribute__((ext_vector_type(2)));

// instant-ngp style bit expansion (<=10-bit inputs)
__device__ __forceinline__ unsigned expand3(unsigned v) {
    v = (v * 0x00010001u) & 0xFF0000FFu;
    v = (v * 0x00000101u) & 0x0F00F00Fu;
    v = (v * 0x00000011u) & 0xC30C30C3u;
    v = (v * 0x00000005u) & 0x49249249u;
    return v;
}
// extract every 3rd bit starting at bit 0
__device__ __forceinline__ unsigned compact3(unsigned v) {
    v &= 0x49249249u;
    v = (v | (v >> 2))  & 0xC30C30C3u;
    v = (v | (v >> 4))  & 0x0F00F00Fu;
    v = (v | (v >> 8))  & 0xFF0000FFu;
    v = (v | (v >> 16)) & 0x000003FFu;
    return v;
}
// LDS swizzle: inject morton bits 7,8,10 into bank bits 2,3,4 (bits 0,1 preserved -> b128 ok)
__device__ __forceinline__ int swz(int m) {
    return (((m >> 7) & 1) << 2) ^ (((m >> 8) & 1) << 3) ^ (((m >> 10) & 1) << 4);
}

__device__ __forceinline__ f32x4 merge4(f32x4 v, f32x4 s) {
    f32x4 r;
    r.x = (v.x >= 0.f && s.x >= 0.f) ? fmaxf(v.x * DECAY, s.x) : v.x;
    r.y = (v.y >= 0.f && s.y >= 0.f) ? fmaxf(v.y * DECAY, s.y) : v.y;
    r.z = (v.z >= 0.f && s.z >= 0.f) ? fmaxf(v.z * DECAY, s.z) : v.z;
    r.w = (v.w >= 0.f && s.w >= 0.f) ? fmaxf(v.w * DECAY, s.w) : v.w;
    return r;
}

// One block = one (t, 16^3 cube). Phase A: coalesced sigma -> LDS morton transpose.
// Phase B: each thread owns 16 consecutive morton elems (2 bitfield bytes).
// NOTE: plain cached loads/stores on purpose — L3 retains in/out lines across
// graph replays (R3 post-mortem: nontemporal hints cost +210 MB HBM traffic/replay).
__global__ __launch_bounds__(256, 6) void
pass1(const float* __restrict__ dg, const float* __restrict__ sg,
      float* __restrict__ out_grid, float* __restrict__ out_bits,
      float* __restrict__ partials)
{
    __shared__ float smem[4096];          // 16 KB
    __shared__ float wsum[4];
    const int blk  = blockIdx.x;          // t*512 + cube_morton
    const int t    = blk >> 9;
    const int cube = blk & 511;
    const int base = t * G3;
    const int tid  = threadIdx.x;
    const int jg0  = base + (cube << 12) + (tid << 4);   // first of 16 morton elems

    // ---- issue density loads EARLY (independent of LDS phase) ----
    const f32x4* dgp = reinterpret_cast<const f32x4*>(dg + jg0);
    const f32x4 v0 = dgp[0];
    const f32x4 v1 = dgp[1];
    const f32x4 v2 = dgp[2];
    const f32x4 v3 = dgp[3];

    // ---- Phase A: linear sigma -> LDS (local morton, swizzled) ----
    const unsigned Xc = compact3((unsigned)cube);
    const unsigned Yc = compact3((unsigned)cube >> 1);
    const unsigned Zc = compact3((unsigned)cube >> 2);
    const float* __restrict__ sgt = sg + base + (int)((Xc << 18) | (Yc << 11) | (Zc << 4));
    #pragma unroll
    for (int k = 0; k < 4; ++k) {
        const int c  = tid + (k << 8);              // 0..1023
        const int lx = c >> 6;
        const int ly = (c >> 2) & 15;
        const int lz = (c & 3) << 2;
        const f32x4 s = *reinterpret_cast<const f32x4*>(sgt + (lx << 14) + (ly << 7) + lz);
        const int m  = (int)(expand3((unsigned)lx) | (expand3((unsigned)ly) << 1)
                           | (expand3((unsigned)lz) << 2));   // bits 2,5 clear
        const int mb = m ^ swz(m);
        smem[mb]      = s.x;   // z+0
        smem[mb ^ 4]  = s.y;   // z+1 (morton +4)
        smem[mb ^ 32] = s.z;   // z+2 (morton +32)
        smem[mb ^ 36] = s.w;   // z+3
    }
    __syncthreads();

    // ---- Phase B: 16 consecutive morton elems, batched LDS reads ----
    const int j = tid << 4;
    const int b = j ^ swz(j);                       // 16B-aligned (swz touches bits 2..4)
    const f32x4 s0 = *reinterpret_cast<const f32x4*>(&smem[b]);
    const f32x4 s1 = *reinterpret_cast<const f32x4*>(&smem[b ^ 4]);
    const f32x4 s2 = *reinterpret_cast<const f32x4*>(&smem[b ^ 8]);
    const f32x4 s3 = *reinterpret_cast<const f32x4*>(&smem[b ^ 12]);

    const f32x4 r0 = merge4(v0, s0);
    const f32x4 r1 = merge4(v1, s1);
    const f32x4 r2 = merge4(v2, s2);
    const f32x4 r3 = merge4(v3, s3);

    f32x4* ogp = reinterpret_cast<f32x4*>(out_grid + jg0);
    ogp[0] = r0;
    ogp[1] = r1;
    ogp[2] = r2;
    ogp[3] = r3;

    float lsum = fmaxf(r0.x, 0.f) + fmaxf(r0.y, 0.f) + fmaxf(r0.z, 0.f) + fmaxf(r0.w, 0.f)
               + fmaxf(r1.x, 0.f) + fmaxf(r1.y, 0.f) + fmaxf(r1.z, 0.f) + fmaxf(r1.w, 0.f)
               + fmaxf(r2.x, 0.f) + fmaxf(r2.y, 0.f) + fmaxf(r2.z, 0.f) + fmaxf(r2.w, 0.f)
               + fmaxf(r3.x, 0.f) + fmaxf(r3.y, 0.f) + fmaxf(r3.z, 0.f) + fmaxf(r3.w, 0.f);

    // two full bitfield bytes per thread (assuming thresh == DTH; fixed up iff mean < DTH)
    const int byte0 = (r0.x > DTH ? 1 : 0)  | (r0.y > DTH ? 2 : 0)  |
                      (r0.z > DTH ? 4 : 0)  | (r0.w > DTH ? 8 : 0)  |
                      (r1.x > DTH ? 16 : 0) | (r1.y > DTH ? 32 : 0) |
                      (r1.z > DTH ? 64 : 0) | (r1.w > DTH ? 128 : 0);
    const int byte1 = (r2.x > DTH ? 1 : 0)  | (r2.y > DTH ? 2 : 0)  |
                      (r2.z > DTH ? 4 : 0)  | (r2.w > DTH ? 8 : 0)  |
                      (r3.x > DTH ? 16 : 0) | (r3.y > DTH ? 32 : 0) |
                      (r3.z > DTH ? 64 : 0) | (r3.w > DTH ? 128 : 0);
    f32x2 bb; bb.x = (float)byte0; bb.y = (float)byte1;
    *reinterpret_cast<f32x2*>(out_bits + (jg0 >> 3)) = bb;

    // block reduction of clip-sum (4 waves)
    #pragma unroll
    for (int off = 32; off; off >>= 1) lsum += __shfl_down(lsum, off, 64);
    if ((tid & 63) == 0) wsum[tid >> 6] = lsum;
    __syncthreads();
    if (tid == 0)
        partials[blk] = wsum[0] + wsum[1] + wsum[2] + wsum[3];
}

__global__ __launch_bounds__(1024) void
reduce_thresh(const float* __restrict__ partials, float* __restrict__ thresh)
{
    float s = 0.f;
    for (int i = threadIdx.x; i < NBLK1; i += 1024) s += partials[i];
    #pragma unroll
    for (int off = 32; off; off >>= 1) s += __shfl_down(s, off, 64);
    __shared__ float wsum[16];
    if ((threadIdx.x & 63) == 0) wsum[threadIdx.x >> 6] = s;
    __syncthreads();
    if (threadIdx.x == 0) {
        float tot = 0.f;
        #pragma unroll
        for (int i = 0; i < 16; ++i) tot += wsum[i];
        thresh[0] = fminf(tot / (float)NTOT, DTH);
    }
}

// Fallback: only does work if mean < DTH (thresh != DTH). Early-exits otherwise.
__global__ __launch_bounds__(256) void
fix_bits(const float* __restrict__ grid, const float* __restrict__ thresh,
         float* __restrict__ out_bits)
{
    const float th = thresh[0];
    if (th == DTH) return;                        // common case: nothing to do
    const int n = blockIdx.x * 256 + threadIdx.x; // byte index < NBYTES_OUT
    const float4* g = reinterpret_cast<const float4*>(grid) + (n << 1);
    const float4 a = g[0], b = g[1];
    int byte = (a.x > th ? 1 : 0)   | (a.y > th ? 2 : 0)   |
               (a.z > th ? 4 : 0)   | (a.w > th ? 8 : 0)   |
               (b.x > th ? 16 : 0)  | (b.y > th ? 32 : 0)  |
               (b.z > th ? 64 : 0)  | (b.w > th ? 128 : 0);
    out_bits[n] = (float)byte;
}

extern "C" void kernel_launch(void* const* d_in, const int* in_sizes, int n_in,
                              void* d_out, int out_size, void* d_ws, size_t ws_size,
                              hipStream_t stream)
{
    const float* dg = (const float*)d_in[0];   // density_grid [T,1,G^3]
    const float* sg = (const float*)d_in[1];   // sigmas       [T,1,G^3]
    float* out_grid = (float*)d_out;           // [T,1,G^3]
    float* out_bits = out_grid + NTOT;         // [T, G^3/8] as float values
    float* partials = (float*)d_ws;            // NBLK1 floats
    float* thresh   = partials + NBLK1;        // 1 float

    pass1<<<NBLK1, 256, 0, stream>>>(dg, sg, out_grid, out_bits, partials);
    reduce_thresh<<<1, 1024, 0, stream>>>(partials, thresh);
    fix_bits<<<NBYTES_OUT / 256, 256, 0, stream>>>(out_grid, thresh, out_bits);
}

// Round 5
// 165.756 us; speedup vs baseline: 1.5764x; 1.0890x over previous
//
#include <hip/hip_runtime.h>

#define G    128
#define G3   (G * G * G)          // 2097152
#define TDIM 32
#define NTOT (TDIM * G3)          // 67108864
#define NBYTES_OUT (NTOT / 8)     // 8388608
#define DECAY 0.95f
#define DTH   0.01f
#define NBLK  (TDIM * 256)        // 8192 blocks, each = one (t, z-paired cube pair 16x16x32)

typedef float f32x4 __attribute__((ext_vector_type(4)));
typedef float f32x2 __attribute__((ext_vector_type(2)));

// instant-ngp style bit expansion (<=10-bit inputs)
__device__ __forceinline__ unsigned expand3(unsigned v) {
    v = (v * 0x00010001u) & 0xFF0000FFu;
    v = (v * 0x00000101u) & 0x0F00F00Fu;
    v = (v * 0x00000011u) & 0xC30C30C3u;
    v = (v * 0x00000005u) & 0x49249249u;
    return v;
}
// extract every 3rd bit starting at bit 0
__device__ __forceinline__ unsigned compact3(unsigned v) {
    v &= 0x49249249u;
    v = (v | (v >> 2))  & 0xC30C30C3u;
    v = (v | (v >> 4))  & 0x0F00F00Fu;
    v = (v | (v >> 8))  & 0xFF0000FFu;
    v = (v | (v >> 16)) & 0x000003FFu;
    return v;
}
// LDS swizzle within a 4096-float cube region: inject morton bits 7,8,10 into
// bank bits 2,3,4 (bits 0,1 preserved -> b128 groups stay contiguous)
__device__ __forceinline__ int swz(int m) {
    return (((m >> 7) & 1) << 2) ^ (((m >> 8) & 1) << 3) ^ (((m >> 10) & 1) << 4);
}

__device__ __forceinline__ f32x4 merge4(f32x4 v, f32x4 s) {
    f32x4 r;
    r.x = (v.x >= 0.f && s.x >= 0.f) ? fmaxf(v.x * DECAY, s.x) : v.x;
    r.y = (v.y >= 0.f && s.y >= 0.f) ? fmaxf(v.y * DECAY, s.y) : v.y;
    r.z = (v.z >= 0.f && s.z >= 0.f) ? fmaxf(v.z * DECAY, s.z) : v.z;
    r.w = (v.w >= 0.f && s.w >= 0.f) ? fmaxf(v.w * DECAY, s.w) : v.w;
    return r;
}

// One block = one (t, cube pair {c0, c0|4}) = 16x16x32 region, 8192 elems.
// Sigma rows are 32 consecutive floats = full 128B lines, fully consumed in-block.
// Plain cached loads/stores on purpose (R3 post-mortem: nt bypasses L3 retention,
// +210 MB HBM/replay).
__global__ __launch_bounds__(512, 8) void
pass1(const float* __restrict__ dg, const float* __restrict__ sg,
      float* __restrict__ out_grid, float* __restrict__ out_bits,
      float* __restrict__ partials)
{
    __shared__ float smem[8192];          // 32 KB: two cube regions of 4096
    __shared__ float wsum[8];
    const int blk  = blockIdx.x;          // t*256 + pair
    const int t    = blk >> 8;
    const int pp   = blk & 255;
    const int c0   = ((pp >> 2) << 3) | (pp & 3);   // cube morton with z-bit0 = 0
    const int base = t * G3;
    const int tid  = threadIdx.x;

    // this thread's cube (first 4 waves -> c0, last 4 -> c0|4) and 16 morton elems
    const int cu   = tid >> 8;
    const int off  = (tid & 255) << 4;
    const int cube = c0 | (cu << 2);
    const int jg0  = base + (cube << 12) + off;

    // ---- issue density loads EARLY (independent of LDS phase) ----
    const f32x4* dgp = reinterpret_cast<const f32x4*>(dg + jg0);
    const f32x4 v0 = dgp[0];
    const f32x4 v1 = dgp[1];
    const f32x4 v2 = dgp[2];
    const f32x4 v3 = dgp[3];

    // ---- Phase A: linear sigma (full 128B rows) -> LDS (per-cube morton, swizzled) ----
    const unsigned Xc = compact3((unsigned)c0);
    const unsigned Yc = compact3((unsigned)c0 >> 1);
    const unsigned Zc = compact3((unsigned)c0 >> 2);       // even
    const float* __restrict__ sgt = sg + base + (int)((Xc << 18) | (Yc << 11) | (Zc << 4));
    #pragma unroll
    for (int k = 0; k < 4; ++k) {
        const int c   = tid + (k << 9);             // 0..2047
        const int lx  = c >> 7;                     // [0,16)
        const int ly  = (c >> 3) & 15;              // [0,16)
        const int lz  = (c & 7) << 2;               // {0,4,...,28}
        const f32x4 s = *reinterpret_cast<const f32x4*>(sgt + (lx << 14) + (ly << 7) + lz);
        const int cs  = (lz >> 4) << 12;            // cube region select
        const int m   = (int)(expand3((unsigned)lx) | (expand3((unsigned)ly) << 1)
                            | (expand3((unsigned)(lz & 15)) << 2));  // bits 2,5 clear
        const int mb  = cs + (m ^ swz(m));
        smem[mb]      = s.x;   // z+0
        smem[mb ^ 4]  = s.y;   // z+1 (morton +4)
        smem[mb ^ 32] = s.z;   // z+2 (morton +32)
        smem[mb ^ 36] = s.w;   // z+3
    }
    __syncthreads();

    // ---- Phase B: 16 consecutive morton elems, batched LDS reads ----
    const int b = (cu << 12) + (off ^ swz(off));    // 16B-aligned (swz touches bits 2..4)
    const f32x4 s0 = *reinterpret_cast<const f32x4*>(&smem[b]);
    const f32x4 s1 = *reinterpret_cast<const f32x4*>(&smem[b ^ 4]);
    const f32x4 s2 = *reinterpret_cast<const f32x4*>(&smem[b ^ 8]);
    const f32x4 s3 = *reinterpret_cast<const f32x4*>(&smem[b ^ 12]);

    const f32x4 r0 = merge4(v0, s0);
    const f32x4 r1 = merge4(v1, s1);
    const f32x4 r2 = merge4(v2, s2);
    const f32x4 r3 = merge4(v3, s3);

    f32x4* ogp = reinterpret_cast<f32x4*>(out_grid + jg0);
    ogp[0] = r0;
    ogp[1] = r1;
    ogp[2] = r2;
    ogp[3] = r3;

    float lsum = fmaxf(r0.x, 0.f) + fmaxf(r0.y, 0.f) + fmaxf(r0.z, 0.f) + fmaxf(r0.w, 0.f)
               + fmaxf(r1.x, 0.f) + fmaxf(r1.y, 0.f) + fmaxf(r1.z, 0.f) + fmaxf(r1.w, 0.f)
               + fmaxf(r2.x, 0.f) + fmaxf(r2.y, 0.f) + fmaxf(r2.z, 0.f) + fmaxf(r2.w, 0.f)
               + fmaxf(r3.x, 0.f) + fmaxf(r3.y, 0.f) + fmaxf(r3.z, 0.f) + fmaxf(r3.w, 0.f);

    // two full bitfield bytes per thread (assuming thresh == DTH; fixed up iff mean < DTH)
    const int byte0 = (r0.x > DTH ? 1 : 0)  | (r0.y > DTH ? 2 : 0)  |
                      (r0.z > DTH ? 4 : 0)  | (r0.w > DTH ? 8 : 0)  |
                      (r1.x > DTH ? 16 : 0) | (r1.y > DTH ? 32 : 0) |
                      (r1.z > DTH ? 64 : 0) | (r1.w > DTH ? 128 : 0);
    const int byte1 = (r2.x > DTH ? 1 : 0)  | (r2.y > DTH ? 2 : 0)  |
                      (r2.z > DTH ? 4 : 0)  | (r2.w > DTH ? 8 : 0)  |
                      (r3.x > DTH ? 16 : 0) | (r3.y > DTH ? 32 : 0) |
                      (r3.z > DTH ? 64 : 0) | (r3.w > DTH ? 128 : 0);
    f32x2 bb; bb.x = (float)byte0; bb.y = (float)byte1;
    *reinterpret_cast<f32x2*>(out_bits + (jg0 >> 3)) = bb;

    // block reduction of clip-sum (8 waves)
    #pragma unroll
    for (int offl = 32; offl; offl >>= 1) lsum += __shfl_down(lsum, offl, 64);
    if ((tid & 63) == 0) wsum[tid >> 6] = lsum;
    __syncthreads();
    if (tid == 0) {
        float tot = 0.f;
        #pragma unroll
        for (int i = 0; i < 8; ++i) tot += wsum[i];
        partials[blk] = tot;
    }
}

__global__ __launch_bounds__(1024) void
reduce_thresh(const float* __restrict__ partials, float* __restrict__ thresh)
{
    float s = 0.f;
    for (int i = threadIdx.x; i < NBLK; i += 1024) s += partials[i];
    #pragma unroll
    for (int off = 32; off; off >>= 1) s += __shfl_down(s, off, 64);
    __shared__ float wsum[16];
    if ((threadIdx.x & 63) == 0) wsum[threadIdx.x >> 6] = s;
    __syncthreads();
    if (threadIdx.x == 0) {
        float tot = 0.f;
        #pragma unroll
        for (int i = 0; i < 16; ++i) tot += wsum[i];
        thresh[0] = fminf(tot / (float)NTOT, DTH);
    }
}

// Fallback: only does work if mean < DTH (thresh != DTH). Early-exits otherwise.
// Small grid + stride loop so the common (inactive) case costs ~nothing.
__global__ __launch_bounds__(256) void
fix_bits(const float* __restrict__ grid, const float* __restrict__ thresh,
         float* __restrict__ out_bits)
{
    const float th = thresh[0];
    if (th == DTH) return;                        // common case: nothing to do
    for (int n = blockIdx.x * 256 + threadIdx.x; n < NBYTES_OUT; n += 256 * 1024) {
        const float4* g = reinterpret_cast<const float4*>(grid) + (n << 1);
        const float4 a = g[0], b = g[1];
        int byte = (a.x > th ? 1 : 0)   | (a.y > th ? 2 : 0)   |
                   (a.z > th ? 4 : 0)   | (a.w > th ? 8 : 0)   |
                   (b.x > th ? 16 : 0)  | (b.y > th ? 32 : 0)  |
                   (b.z > th ? 64 : 0)  | (b.w > th ? 128 : 0);
        out_bits[n] = (float)byte;
    }
}

extern "C" void kernel_launch(void* const* d_in, const int* in_sizes, int n_in,
                              void* d_out, int out_size, void* d_ws, size_t ws_size,
                              hipStream_t stream)
{
    const float* dg = (const float*)d_in[0];   // density_grid [T,1,G^3]
    const float* sg = (const float*)d_in[1];   // sigmas       [T,1,G^3]
    float* out_grid = (float*)d_out;           // [T,1,G^3]
    float* out_bits = out_grid + NTOT;         // [T, G^3/8] as float values
    float* partials = (float*)d_ws;            // NBLK floats
    float* thresh   = partials + NBLK;         // 1 float

    pass1<<<NBLK, 512, 0, stream>>>(dg, sg, out_grid, out_bits, partials);
    reduce_thresh<<<1, 1024, 0, stream>>>(partials, thresh);
    fix_bits<<<1024, 256, 0, stream>>>(out_grid, thresh, out_bits);
}

// Round 6
// 160.765 us; speedup vs baseline: 1.6253x; 1.0310x over previous
//
#include <hip/hip_runtime.h>

#define G    128
#define G3   (G * G * G)          // 2097152
#define TDIM 32
#define NTOT (TDIM * G3)          // 67108864
#define NBYTES_OUT (NTOT / 8)     // 8388608
#define DECAY 0.95f
#define DTH   0.01f
#define NBLK  (TDIM * 256)        // 8192 blocks: one (t, 8x8x128 slab) each

typedef float f32x4 __attribute__((ext_vector_type(4)));
typedef float f32x2 __attribute__((ext_vector_type(2)));

// instant-ngp style bit expansion (<=10-bit inputs)
__device__ __forceinline__ unsigned expand3(unsigned v) {
    v = (v * 0x00010001u) & 0xFF0000FFu;
    v = (v * 0x00000101u) & 0x0F00F00Fu;
    v = (v * 0x00000011u) & 0xC30C30C3u;
    v = (v * 0x00000005u) & 0x49249249u;
    return v;
}

// LDS address swizzle (pure function of float index, applied on BOTH sides):
// inject bit12 (=x2) into bank bit 3 and bit8 (=y1) into bank bit 4.
// Touches float-index bits 3,4 only -> b128 (bits 0,1) and b64 (bit 0) alignment kept.
__device__ __forceinline__ int swz(int f) {
    return f ^ ((((f >> 12) & 1) << 3) ^ (((f >> 8) & 1) << 4));
}

__device__ __forceinline__ f32x4 merge4(f32x4 v, f32x4 s) {
    f32x4 r;
    r.x = (v.x >= 0.f && s.x >= 0.f) ? fmaxf(v.x * DECAY, s.x) : v.x;
    r.y = (v.y >= 0.f && s.y >= 0.f) ? fmaxf(v.y * DECAY, s.y) : v.y;
    r.z = (v.z >= 0.f && s.z >= 0.f) ? fmaxf(v.z * DECAY, s.z) : v.z;
    r.w = (v.w >= 0.f && s.w >= 0.f) ? fmaxf(v.w * DECAY, s.w) : v.w;
    return r;
}

// One block = one (t, 8x8x128 slab). All streams long-contiguous:
//   sigma: 8 chunks x 4KB; density/grid: 16 runs x 2KB; bits: 16 runs x 256B.
// LDS layout = slab-linear f = x*1024 + y*128 + z (swizzled). Phase A writes
// b128 linear (conflict-free); phase B reads 8x b64 z-pairs (2-way max).
// Plain cached loads/stores (R3 post-mortem: nt defeats L3 retention).
__global__ __launch_bounds__(512, 8) void
pass1(const float* __restrict__ dg, const float* __restrict__ sg,
      float* __restrict__ out_grid, float* __restrict__ out_bits,
      float* __restrict__ partials)
{
    __shared__ float smem[8192];          // 32 KB
    __shared__ float wsum[8];
    const int blk  = blockIdx.x;          // t*256 + slab
    const int t    = blk >> 8;
    const int pp   = blk & 255;
    const int sx   = pp & 15;             // slab x (x = 8*sx + lx)
    const int sy   = pp >> 4;             // slab y
    const int base = t * G3;
    const int tid  = threadIdx.x;

    // morton decomposition: slab-fixed high bits + run (z3..z6) + 9-bit local
    const int m_fixed = (int)((expand3((unsigned)sx) << 9) | (expand3((unsigned)sy) << 10));
    const int r   = tid >> 5;                       // run 0..15 -> z high bits
    const int o   = (tid & 31) << 4;                // 16 consecutive morton within run
    const int jg0 = base + m_fixed + (int)(expand3((unsigned)r) << 11) + o;

    // ---- issue density loads EARLY (independent of LDS phase) ----
    const f32x4* dgp = reinterpret_cast<const f32x4*>(dg + jg0);
    const f32x4 v0 = dgp[0];
    const f32x4 v1 = dgp[1];
    const f32x4 v2 = dgp[2];
    const f32x4 v3 = dgp[3];

    // ---- Phase A: contiguous sigma chunks -> LDS slab-linear (b128, conflict-free) ----
    const float* __restrict__ sgt = sg + base + (sx << 17) + (sy << 10); // sx*8*16384 + sy*8*128
    #pragma unroll
    for (int k = 0; k < 4; ++k) {
        const int c   = tid + (k << 9);             // 0..2047 float4 id
        const int x   = c >> 8;                     // [0,8)
        const int rem = c & 255;                    // (y,z/4) within x-chunk, contiguous
        const f32x4 s = *reinterpret_cast<const f32x4*>(sgt + (x << 14) + (rem << 2));
        *reinterpret_cast<f32x4*>(&smem[swz((x << 10) + (rem << 2))]) = s;
    }
    __syncthreads();

    // ---- Phase B: 8x ds_read_b64 z0-pairs -> 16 morton-ordered elems ----
    const int lb = tid & 31;                        // bits: y1 z1 x2 y2 z2
    const int y1 = lb & 1, z1 = (lb >> 1) & 1, x2 = (lb >> 2) & 1;
    const int y2 = (lb >> 3) & 1, z2 = (lb >> 4) & 1;
    const int zz = (z1 << 1) + (z2 << 2) + (r << 3);   // z minus z0 (even)

    f32x2 p0, p1, p2, p3, p4, p5, p6, p7;
    {
        const int xA = 2 * 0 + 4 * x2;              // x1=0 (without x0)
        const int xB = 2 * 1 + 4 * x2;              // x1=1
        const int yA = 2 * y1 + 4 * y2;             // without y0
        const int fA = (xA << 10) + (yA << 7) + zz;
        const int fB = (xB << 10) + (yA << 7) + zz;
        p0 = *reinterpret_cast<const f32x2*>(&smem[swz(fA)]);                    // x0=0,y0=0,x1=0
        p1 = *reinterpret_cast<const f32x2*>(&smem[swz(fA + 1024)]);             // x0=1
        p2 = *reinterpret_cast<const f32x2*>(&smem[swz(fA + 128)]);              // y0=1
        p3 = *reinterpret_cast<const f32x2*>(&smem[swz(fA + 1152)]);             // x0=1,y0=1
        p4 = *reinterpret_cast<const f32x2*>(&smem[swz(fB)]);                    // x1=1
        p5 = *reinterpret_cast<const f32x2*>(&smem[swz(fB + 1024)]);
        p6 = *reinterpret_cast<const f32x2*>(&smem[swz(fB + 128)]);
        p7 = *reinterpret_cast<const f32x2*>(&smem[swz(fB + 1152)]);
    }
    f32x4 s0; s0.x = p0.x; s0.y = p1.x; s0.z = p2.x; s0.w = p3.x;   // e0..3  (z0=0,x1=0)
    f32x4 s1; s1.x = p0.y; s1.y = p1.y; s1.z = p2.y; s1.w = p3.y;   // e4..7  (z0=1,x1=0)
    f32x4 s2; s2.x = p4.x; s2.y = p5.x; s2.z = p6.x; s2.w = p7.x;   // e8..11 (z0=0,x1=1)
    f32x4 s3; s3.x = p4.y; s3.y = p5.y; s3.z = p6.y; s3.w = p7.y;   // e12..15

    const f32x4 r0 = merge4(v0, s0);
    const f32x4 r1 = merge4(v1, s1);
    const f32x4 r2 = merge4(v2, s2);
    const f32x4 r3 = merge4(v3, s3);

    f32x4* ogp = reinterpret_cast<f32x4*>(out_grid + jg0);
    ogp[0] = r0;
    ogp[1] = r1;
    ogp[2] = r2;
    ogp[3] = r3;

    float lsum = fmaxf(r0.x, 0.f) + fmaxf(r0.y, 0.f) + fmaxf(r0.z, 0.f) + fmaxf(r0.w, 0.f)
               + fmaxf(r1.x, 0.f) + fmaxf(r1.y, 0.f) + fmaxf(r1.z, 0.f) + fmaxf(r1.w, 0.f)
               + fmaxf(r2.x, 0.f) + fmaxf(r2.y, 0.f) + fmaxf(r2.z, 0.f) + fmaxf(r2.w, 0.f)
               + fmaxf(r3.x, 0.f) + fmaxf(r3.y, 0.f) + fmaxf(r3.z, 0.f) + fmaxf(r3.w, 0.f);

    // two bitfield bytes per thread (assuming thresh == DTH; fixed up iff mean < DTH)
    const int byte0 = (r0.x > DTH ? 1 : 0)  | (r0.y > DTH ? 2 : 0)  |
                      (r0.z > DTH ? 4 : 0)  | (r0.w > DTH ? 8 : 0)  |
                      (r1.x > DTH ? 16 : 0) | (r1.y > DTH ? 32 : 0) |
                      (r1.z > DTH ? 64 : 0) | (r1.w > DTH ? 128 : 0);
    const int byte1 = (r2.x > DTH ? 1 : 0)  | (r2.y > DTH ? 2 : 0)  |
                      (r2.z > DTH ? 4 : 0)  | (r2.w > DTH ? 8 : 0)  |
                      (r3.x > DTH ? 16 : 0) | (r3.y > DTH ? 32 : 0) |
                      (r3.z > DTH ? 64 : 0) | (r3.w > DTH ? 128 : 0);
    f32x2 bb; bb.x = (float)byte0; bb.y = (float)byte1;
    *reinterpret_cast<f32x2*>(out_bits + (jg0 >> 3)) = bb;

    // block reduction of clip-sum (8 waves)
    #pragma unroll
    for (int offl = 32; offl; offl >>= 1) lsum += __shfl_down(lsum, offl, 64);
    if ((tid & 63) == 0) wsum[tid >> 6] = lsum;
    __syncthreads();
    if (tid == 0) {
        float tot = 0.f;
        #pragma unroll
        for (int i = 0; i < 8; ++i) tot += wsum[i];
        partials[blk] = tot;
    }
}

__global__ __launch_bounds__(1024) void
reduce_thresh(const float* __restrict__ partials, float* __restrict__ thresh)
{
    float s = 0.f;
    for (int i = threadIdx.x; i < NBLK; i += 1024) s += partials[i];
    #pragma unroll
    for (int off = 32; off; off >>= 1) s += __shfl_down(s, off, 64);
    __shared__ float wsum[16];
    if ((threadIdx.x & 63) == 0) wsum[threadIdx.x >> 6] = s;
    __syncthreads();
    if (threadIdx.x == 0) {
        float tot = 0.f;
        #pragma unroll
        for (int i = 0; i < 16; ++i) tot += wsum[i];
        thresh[0] = fminf(tot / (float)NTOT, DTH);
    }
}

// Fallback: only does work if mean < DTH (thresh != DTH). Early-exits otherwise.
__global__ __launch_bounds__(256) void
fix_bits(const float* __restrict__ grid, const float* __restrict__ thresh,
         float* __restrict__ out_bits)
{
    const float th = thresh[0];
    if (th == DTH) return;                        // common case: nothing to do
    for (int n = blockIdx.x * 256 + threadIdx.x; n < NBYTES_OUT; n += 256 * 1024) {
        const float4* g = reinterpret_cast<const float4*>(grid) + (n << 1);
        const float4 a = g[0], b = g[1];
        int byte = (a.x > th ? 1 : 0)   | (a.y > th ? 2 : 0)   |
                   (a.z > th ? 4 : 0)   | (a.w > th ? 8 : 0)   |
                   (b.x > th ? 16 : 0)  | (b.y > th ? 32 : 0)  |
                   (b.z > th ? 64 : 0)  | (b.w > th ? 128 : 0);
        out_bits[n] = (float)byte;
    }
}

extern "C" void kernel_launch(void* const* d_in, const int* in_sizes, int n_in,
                              void* d_out, int out_size, void* d_ws, size_t ws_size,
                              hipStream_t stream)
{
    const float* dg = (const float*)d_in[0];   // density_grid [T,1,G^3]
    const float* sg = (const float*)d_in[1];   // sigmas       [T,1,G^3]
    float* out_grid = (float*)d_out;           // [T,1,G^3]
    float* out_bits = out_grid + NTOT;         // [T, G^3/8] as float values
    float* partials = (float*)d_ws;            // NBLK floats
    float* thresh   = partials + NBLK;         // 1 float

    pass1<<<NBLK, 512, 0, stream>>>(dg, sg, out_grid, out_bits, partials);
    reduce_thresh<<<1, 1024, 0, stream>>>(partials, thresh);
    fix_bits<<<1024, 256, 0, stream>>>(out_grid, thresh, out_bits);
}

// Round 7
// 158.212 us; speedup vs baseline: 1.6516x; 1.0161x over previous
//
#include <hip/hip_runtime.h>

#define G    128
#define G3   (G * G * G)          // 2097152
#define TDIM 32
#define NTOT (TDIM * G3)          // 67108864
#define NBYTES_OUT (NTOT / 8)     // 8388608
#define DECAY 0.95f
#define DTH   0.01f
#define NBLK  (TDIM * 256)        // 8192 blocks: one (t, 8x8x128 slab) each

typedef float f32x4 __attribute__((ext_vector_type(4)));
typedef float f32x2 __attribute__((ext_vector_type(2)));

// instant-ngp style bit expansion (<=10-bit inputs)
__device__ __forceinline__ unsigned expand3(unsigned v) {
    v = (v * 0x00010001u) & 0xFF0000FFu;
    v = (v * 0x00000101u) & 0x0F00F00Fu;
    v = (v * 0x00000011u) & 0xC30C30C3u;
    v = (v * 0x00000005u) & 0x49249249u;
    return v;
}

// LDS swizzle (pure function of slab-linear float index f = x<<10 | y<<7 | z):
// inject x1 (bit11) -> bank bit 2, y1 (bit8) -> bank bit 3, x2 (bit12) -> bank bit 4.
// Phase-A b128 writes: inputs are wave-uniform -> stays linear conflict-free.
// Phase-B b32 reads: banks become f(z0,z1,x1,y1,x2) = 32 distinct over half-wave,
// lanes i / i+32 alias 2-way (free per m136).
__device__ __forceinline__ int swz(int f) {
    return f ^ ((((f >> 11) & 1) << 2) | (((f >> 8) & 1) << 3) | (((f >> 12) & 1) << 4));
}

__device__ __forceinline__ f32x4 merge4(f32x4 v, f32x4 s) {
    f32x4 r;
    r.x = (v.x >= 0.f && s.x >= 0.f) ? fmaxf(v.x * DECAY, s.x) : v.x;
    r.y = (v.y >= 0.f && s.y >= 0.f) ? fmaxf(v.y * DECAY, s.y) : v.y;
    r.z = (v.z >= 0.f && s.z >= 0.f) ? fmaxf(v.z * DECAY, s.z) : v.z;
    r.w = (v.w >= 0.f && s.w >= 0.f) ? fmaxf(v.w * DECAY, s.w) : v.w;
    return r;
}

// One block = one (t, 8x8x128 slab). Wave = 2 runs (8x8x8 subcubes) = 1024 morton floats.
// Lane i owns float4s {i, i+64, i+128, i+192} of the wave region -> every global
// load/store instruction is a contiguous 1024B wave transaction (full-line writes;
// CDNA L1 is write-through so partial-line stores cost 4x at L2 — R6 post-mortem).
// Plain cached accesses on purpose (R3 post-mortem: nt defeats L3 retention).
__global__ __launch_bounds__(512, 8) void
pass1(const float* __restrict__ dg, const float* __restrict__ sg,
      float* __restrict__ out_grid, float* __restrict__ out_bits,
      float* __restrict__ partials)
{
    __shared__ float smem[8192];          // 32 KB
    __shared__ float wsum[8];
    const int blk  = blockIdx.x;          // t*256 + slab
    const int t    = blk >> 8;
    const int pp   = blk & 255;
    const int sx   = pp & 15;             // slab x (x = 8*sx + lx)
    const int sy   = pp >> 4;             // slab y
    const int base = t * G3;
    const int tid  = threadIdx.x;
    const int w    = tid >> 6;            // wave 0..7 -> runs 2w, 2w+1
    const int i    = tid & 63;            // lane

    // global morton base of this wave's run A (run 2w); run B = +2048 floats
    const int m_fixed = (int)((expand3((unsigned)sx) << 9) | (expand3((unsigned)sy) << 10));
    const int jgA = base + m_fixed + ((int)expand3((unsigned)w) << 14) + (i << 2);

    // ---- density loads: 4x fully-coalesced 1024B wave transactions, issued early ----
    const f32x4* dgp = reinterpret_cast<const f32x4*>(dg + jgA);
    const f32x4 v0 = dgp[0];     // run A, float4 #i
    const f32x4 v1 = dgp[64];    // run A, float4 #(64+i)
    const f32x4 v2 = dgp[512];   // run B, float4 #i
    const f32x4 v3 = dgp[576];   // run B, float4 #(64+i)

    // ---- Phase A: contiguous sigma chunks -> LDS slab-linear (b128, conflict-free) ----
    const float* __restrict__ sgt = sg + base + (sx << 17) + (sy << 10);
    #pragma unroll
    for (int k = 0; k < 4; ++k) {
        const int c   = tid + (k << 9);             // 0..2047 float4 id
        const int x   = c >> 8;                     // [0,8)
        const int rem = c & 255;                    // y*32 + z/4, contiguous
        const f32x4 s = *reinterpret_cast<const f32x4*>(sgt + (x << 14) + (rem << 2));
        *reinterpret_cast<f32x4*>(&smem[swz((x << 10) + (rem << 2))]) = s;
    }
    __syncthreads();

    // ---- Phase B: 16x ds_read_b32 (swizzled, ~2-way max) -> 4 morton float4s ----
    // float4 #n (n = 64*(c&1) + i) of run r: morton m=4n ->
    //   z0=n&1, x1=n>>1, y1=n>>2, z1=n>>3, x2=n>>4, y2=n>>5, z2=n>>6
    //   f = z0 | z1<<1 | z2<<2 | r<<3 | y1<<8 | y2<<9 | x1<<11 | x2<<12
    //   4 floats at f, f+1024 (x0), f+128 (y0), f+1152
    const int fi = (i & 1) | (((i >> 3) & 1) << 1) | (((i >> 2) & 1) << 8)
                 | (((i >> 5) & 1) << 9) | (((i >> 1) & 1) << 11) | (((i >> 4) & 1) << 12);
    const int S  = (((fi >> 11) & 1) << 2) | (((fi >> 8) & 1) << 3) | (((fi >> 12) & 1) << 4);
    const int A  = w << 4;                          // run bits (r = 2w + c>>1 -> +8 per c>>1)
    // fi bits {0,1,8,9,11,12} disjoint from (A + cofs) bits {2..6}; swz(f) = fi | ((A+cofs)^S)
    const float* sp0 = &smem[fi | ((A + 0)  ^ S)];  // c0: run A, z2=0
    const float* sp1 = &smem[fi | ((A + 4)  ^ S)];  // c1: run A, z2=1
    const float* sp2 = &smem[fi | ((A + 8)  ^ S)];  // c2: run B, z2=0
    const float* sp3 = &smem[fi | ((A + 12) ^ S)];  // c3: run B, z2=1
    f32x4 s0; s0.x = sp0[0]; s0.y = sp0[1024]; s0.z = sp0[128]; s0.w = sp0[1152];
    f32x4 s1; s1.x = sp1[0]; s1.y = sp1[1024]; s1.z = sp1[128]; s1.w = sp1[1152];
    f32x4 s2; s2.x = sp2[0]; s2.y = sp2[1024]; s2.z = sp2[128]; s2.w = sp2[1152];
    f32x4 s3; s3.x = sp3[0]; s3.y = sp3[1024]; s3.z = sp3[128]; s3.w = sp3[1152];

    const f32x4 r0 = merge4(v0, s0);
    const f32x4 r1 = merge4(v1, s1);
    const f32x4 r2 = merge4(v2, s2);
    const f32x4 r3 = merge4(v3, s3);

    // ---- grid stores: 4x fully-coalesced 1024B wave transactions ----
    f32x4* ogp = reinterpret_cast<f32x4*>(out_grid + jgA);
    ogp[0]   = r0;
    ogp[64]  = r1;
    ogp[512] = r2;
    ogp[576] = r3;

    float lsum = fmaxf(r0.x, 0.f) + fmaxf(r0.y, 0.f) + fmaxf(r0.z, 0.f) + fmaxf(r0.w, 0.f)
               + fmaxf(r1.x, 0.f) + fmaxf(r1.y, 0.f) + fmaxf(r1.z, 0.f) + fmaxf(r1.w, 0.f)
               + fmaxf(r2.x, 0.f) + fmaxf(r2.y, 0.f) + fmaxf(r2.z, 0.f) + fmaxf(r2.w, 0.f)
               + fmaxf(r3.x, 0.f) + fmaxf(r3.y, 0.f) + fmaxf(r3.z, 0.f) + fmaxf(r3.w, 0.f);

    // ---- bitfield: nibble per chunk, pair-merge via shfl_xor, even lanes store ----
    int n0 = (r0.x > DTH ? 1 : 0) | (r0.y > DTH ? 2 : 0) | (r0.z > DTH ? 4 : 0) | (r0.w > DTH ? 8 : 0);
    int n1 = (r1.x > DTH ? 1 : 0) | (r1.y > DTH ? 2 : 0) | (r1.z > DTH ? 4 : 0) | (r1.w > DTH ? 8 : 0);
    int n2 = (r2.x > DTH ? 1 : 0) | (r2.y > DTH ? 2 : 0) | (r2.z > DTH ? 4 : 0) | (r2.w > DTH ? 8 : 0);
    int n3 = (r3.x > DTH ? 1 : 0) | (r3.y > DTH ? 2 : 0) | (r3.z > DTH ? 4 : 0) | (r3.w > DTH ? 8 : 0);
    const int p0 = __shfl_xor(n0, 1, 64);
    const int p1 = __shfl_xor(n1, 1, 64);
    const int p2 = __shfl_xor(n2, 1, 64);
    const int p3 = __shfl_xor(n3, 1, 64);
    if ((i & 1) == 0) {
        float* bp = out_bits + (jgA >> 3);          // jgA = 8*(...) for even lanes
        bp[0]   = (float)(n0 | (p0 << 4));          // run A bytes [0,32)
        bp[32]  = (float)(n1 | (p1 << 4));          // run A bytes [32,64)
        bp[256] = (float)(n2 | (p2 << 4));          // run B bytes [0,32)
        bp[288] = (float)(n3 | (p3 << 4));          // run B bytes [32,64)
    }

    // block reduction of clip-sum (8 waves)
    #pragma unroll
    for (int offl = 32; offl; offl >>= 1) lsum += __shfl_down(lsum, offl, 64);
    if ((tid & 63) == 0) wsum[tid >> 6] = lsum;
    __syncthreads();
    if (tid == 0) {
        float tot = 0.f;
        #pragma unroll
        for (int k = 0; k < 8; ++k) tot += wsum[k];
        partials[blk] = tot;
    }
}

__global__ __launch_bounds__(1024) void
reduce_thresh(const float* __restrict__ partials, float* __restrict__ thresh)
{
    float s = 0.f;
    for (int i = threadIdx.x; i < NBLK; i += 1024) s += partials[i];
    #pragma unroll
    for (int off = 32; off; off >>= 1) s += __shfl_down(s, off, 64);
    __shared__ float wsum[16];
    if ((threadIdx.x & 63) == 0) wsum[threadIdx.x >> 6] = s;
    __syncthreads();
    if (threadIdx.x == 0) {
        float tot = 0.f;
        #pragma unroll
        for (int i = 0; i < 16; ++i) tot += wsum[i];
        thresh[0] = fminf(tot / (float)NTOT, DTH);
    }
}

// Fallback: only does work if mean < DTH (thresh != DTH). Early-exits otherwise.
__global__ __launch_bounds__(256) void
fix_bits(const float* __restrict__ grid, const float* __restrict__ thresh,
         float* __restrict__ out_bits)
{
    const float th = thresh[0];
    if (th == DTH) return;                        // common case: nothing to do
    for (int n = blockIdx.x * 256 + threadIdx.x; n < NBYTES_OUT; n += 256 * 1024) {
        const float4* g = reinterpret_cast<const float4*>(grid) + (n << 1);
        const float4 a = g[0], b = g[1];
        int byte = (a.x > th ? 1 : 0)   | (a.y > th ? 2 : 0)   |
                   (a.z > th ? 4 : 0)   | (a.w > th ? 8 : 0)   |
                   (b.x > th ? 16 : 0)  | (b.y > th ? 32 : 0)  |
                   (b.z > th ? 64 : 0)  | (b.w > th ? 128 : 0);
        out_bits[n] = (float)byte;
    }
}

extern "C" void kernel_launch(void* const* d_in, const int* in_sizes, int n_in,
                              void* d_out, int out_size, void* d_ws, size_t ws_size,
                              hipStream_t stream)
{
    const float* dg = (const float*)d_in[0];   // density_grid [T,1,G^3]
    const float* sg = (const float*)d_in[1];   // sigmas       [T,1,G^3]
    float* out_grid = (float*)d_out;           // [T,1,G^3]
    float* out_bits = out_grid + NTOT;         // [T, G^3/8] as float values
    float* partials = (float*)d_ws;            // NBLK floats
    float* thresh   = partials + NBLK;         // 1 float

    pass1<<<NBLK, 512, 0, stream>>>(dg, sg, out_grid, out_bits, partials);
    reduce_thresh<<<1, 1024, 0, stream>>>(partials, thresh);
    fix_bits<<<1024, 256, 0, stream>>>(out_grid, thresh, out_bits);
}